// Round 17
// baseline (1704.600 us; speedup 1.0000x reference)
//
#include <hip/hip_runtime.h>
#include <hip/hip_bf16.h>

// SplitRoundGIN: N=100000, E=1200000, D=64, RW=3, L=2, eps=-1 (pure neighbor sum).
// R16 = R15 gathers + bucketed fill: pass1 (bucket_kernel) ballot-appends edges
// into 8 per-XCD-range dense lists (1 global atomic per wave per bucket);
// pass2 (fill_ln fill role) scans its own dense list with ALL lanes active --
// tests the hypothesis that fill's invariant 85-90us across 5 structures is
// exec-mask-sparse wave atomics (1/8 lanes active) wasting atomic throughput.
constexpr int NN  = 100000;
constexpr int EE  = 1200000;
constexpr int D   = 64;
constexpr int CAP = 64;                  // max degree bucket (P(deg>64) ~ 1e-28)
constexpr int ZROW = NN;                 // dedicated all-zero row index
constexpr float LN_EPS = 1e-5f;
constexpr int NXCD = 8;
constexpr int NPX  = (NN + NXCD - 1) / NXCD;     // 12500 nodes per XCD range
constexpr int FILL_GRP = 256;                    // blocks per XCD group
constexpr int FILL_BLOCKS = NXCD * FILL_GRP;     // 2048
constexpr int LN_BLOCKS = (NN * D) / 256;        // 25000
constexpr int NAPW = (NN + 15) / 16;             // 6250 agePacked words
constexpr int EBCAP = 160000;                    // per-bucket capacity (mean 150k, 27 sigma)
constexpr int BUCKET_BLOCKS = 2048;
constexpr int BUCKET_TOT = BUCKET_BLOCKS * 256;  // 524288 threads
constexpr int BUCKET_ITERS = (EE + BUCKET_TOT - 1) / BUCKET_TOT;  // 3

typedef unsigned uint3v __attribute__((ext_vector_type(3)));

// ---- prep: zero cnt/tail, build agePk, zero ZROW rows of hnbf/A1i ----
__global__ void prep_kernel(const int* __restrict__ age, int* __restrict__ cnt,
                            unsigned* __restrict__ agePk, int* __restrict__ tail,
                            __hip_bfloat16* __restrict__ ybf,
                            unsigned short* __restrict__ A1i) {
    int gid = blockIdx.x * blockDim.x + threadIdx.x;
    if (gid < NN) cnt[gid] = 0;
    if (gid < 8) tail[gid] = 0;
    if (gid < NAPW) {
        unsigned w = 0;
        int base = gid * 16;
        #pragma unroll
        for (int k = 0; k < 16; ++k) {
            int idx = base + k;
            unsigned a = (idx < NN) ? (unsigned)age[idx] : 0u;
            w |= (a & 3u) << (2 * k);
        }
        agePk[gid] = w;
    }
    if (gid < 192) {
        A1i[(size_t)ZROW * 192 + gid] = 0;
        if (gid < 64) ybf[(size_t)ZROW * D + gid] = __float2bfloat16(0.f);
    }
}

// ---- pass 1: ballot-aggregated bucketing of edges by dst XCD-range ----
__global__ void bucket_kernel(const int* __restrict__ src, const int* __restrict__ dst,
                              const unsigned* __restrict__ agePk,
                              int* __restrict__ tail, int2* __restrict__ ebuf) {
    int gid  = blockIdx.x * blockDim.x + threadIdx.x;
    int lane = threadIdx.x & 63;
    #pragma unroll
    for (int it = 0; it < BUCKET_ITERS; ++it) {
        int e = it * BUCKET_TOT + gid;
        int x = -1;
        int2 pr;
        if (e < EE) {
            int d = dst[e];
            int s = src[e];
            unsigned aw = agePk[s >> 4];
            int ag = (aw >> ((s & 15) * 2)) & 3;
            x = d / NPX;
            pr.x = d;
            pr.y = s | (ag << 17);
        }
        #pragma unroll
        for (int j = 0; j < NXCD; ++j) {
            unsigned long long mask = __ballot(x == j);
            if (!mask) continue;
            int cntj = __popcll(mask);
            int leader = __ffsll(mask) - 1;
            int base = 0;
            if (lane == leader) base = atomicAdd(&tail[j], cntj);
            base = __shfl(base, leader);
            if (x == j) {
                int off = __popcll(mask & ((1ull << lane) - 1ull));
                ebuf[(size_t)j * EBCAP + base + off] = pr;
            }
        }
    }
}

// ---- pass 2: dense fill (all lanes active) + LN (block-role split) ----
__global__ void fill_ln_kernel(const int2* __restrict__ ebuf, const int* __restrict__ tail,
                               const float* __restrict__ x,
                               int* __restrict__ cnt, int* __restrict__ packed,
                               __hip_bfloat16* __restrict__ ybf) {
    int bid = blockIdx.x;
    if (bid < FILL_BLOCKS) {
        int g    = bid & 7;              // -> XCD via round-robin dispatch
        int grp  = bid >> 3;             // 0..FILL_GRP-1
        int ne   = tail[g];
        const int2* eb = ebuf + (size_t)g * EBCAP;
        int step = FILL_GRP * 256;
        for (int i = grp * 256 + (int)threadIdx.x; i < ne; i += step) {
            int2 pr = eb[i];             // coalesced 8B
            int slot = atomicAdd(&cnt[pr.x], 1);
            if (slot < CAP) packed[(size_t)pr.x * CAP + slot] = pr.y;
        }
        return;
    }
    // LN role
    int gid  = (bid - FILL_BLOCKS) * (int)blockDim.x + (int)threadIdx.x;
    int row  = gid >> 6;
    int lane = gid & 63;
    if (row >= NN) return;
    size_t i = (size_t)row * D + lane;
    float v = x[i];
    float s = v;
    #pragma unroll
    for (int m = 1; m < 64; m <<= 1) s += __shfl_xor(s, m);
    float mu = s * (1.f / 64.f);
    float d = v - mu;
    float q = d * d;
    #pragma unroll
    for (int m = 1; m < 64; m <<= 1) q += __shfl_xor(q, m);
    float r = d * rsqrtf(q * (1.f / 64.f) + LN_EPS);
    ybf[i] = __float2bfloat16(r);
}

__device__ __forceinline__ float2 bf22f2(ushort2 u) {
    float2 r;
    r.x = __uint_as_float((unsigned)u.x << 16);
    r.y = __uint_as_float((unsigned)u.y << 16);
    return r;
}

__device__ __forceinline__ float bfu2f(unsigned u) {
    return __uint_as_float(u << 16);
}

__device__ __forceinline__ unsigned short f2bfu(float v) {
    __hip_bfloat16 b = __float2bfloat16(v);
    return *(const unsigned short*)&b;
}

// Full-row LN over 64 cols held as float2 per lane in a 32-lane group.
__device__ __forceinline__ float2 ln_relu_pair(float2 a, bool relu) {
    float s = a.x + a.y;
    #pragma unroll
    for (int m = 1; m < 32; m <<= 1) s += __shfl_xor(s, m);
    float mu = s * (1.f / 64.f);
    float dx = a.x - mu, dy = a.y - mu;
    float q = dx * dx + dy * dy;
    #pragma unroll
    for (int m = 1; m < 32; m <<= 1) q += __shfl_xor(q, m);
    float rs = rsqrtf(q * (1.f / 64.f) + LN_EPS);
    float2 r;
    r.x = dx * rs;
    r.y = dy * rs;
    if (relu) { r.x = fmaxf(r.x, 0.f); r.y = fmaxf(r.y, 0.f); }
    return r;
}

// layer-1 gather (3 windows via age mask) + LN/ReLU + h1 output writes.
// A1i layout: [node][64][3] bf16 interleaved (384B/node; col c -> w0,w1,w2).
__global__ void gather1_kernel(const __hip_bfloat16* __restrict__ hnbf,
                               const int* __restrict__ cnt,
                               const int* __restrict__ packed,
                               unsigned short* __restrict__ A1i,
                               float* __restrict__ out) {
    int gid  = blockIdx.x * blockDim.x + threadIdx.x;
    int node = gid >> 6;
    int lane = gid & 63;
    if (node >= NN) return;
    int sl = lane & 31;
    int h  = lane >> 5;
    int n  = min(cnt[node], CAP);
    int nc4 = (n + 3) >> 2;
    int mc  = max(nc4 - 1, 0);
    const int* pl = packed + (size_t)node * CAP;   // 256B-aligned
    float2 a0 = {0.f, 0.f}, a1 = {0.f, 0.f}, a2 = {0.f, 0.f};

    {
        int c0 = min(h, mc), c1 = min(h + 2, mc);
        int4 pa = *reinterpret_cast<const int4*>(pl + 4 * c0);
        int4 pb = *reinterpret_cast<const int4*>(pl + 4 * c1);
        int pA[4] = {pa.x, pa.y, pa.z, pa.w};
        int pB[4] = {pb.x, pb.y, pb.z, pb.w};
        #pragma unroll
        for (int k = 0; k < 8; ++k) {
            int i  = (k < 4) ? (4 * h + k) : (4 * (h + 2) + (k - 4));
            int pk = (k < 4) ? pA[k] : pB[k - 4];
            int idx = (i < n) ? (pk & 0x1FFFF) : ZROW;
            const ushort2* row = reinterpret_cast<const ushort2*>(
                hnbf + (size_t)idx * D);
            float2 v = bf22f2(row[sl]);
            int g = pk >> 17;
            a0.x += v.x; a0.y += v.y;
            if (g >= 1) { a1.x += v.x; a1.y += v.y; }
            if (g >= 2) { a2.x += v.x; a2.y += v.y; }
        }
    }
    for (int c = 4 + h; c < nc4; c += 2) {
        int4 pc = *reinterpret_cast<const int4*>(pl + 4 * c);
        int pC[4] = {pc.x, pc.y, pc.z, pc.w};
        #pragma unroll
        for (int k = 0; k < 4; ++k) {
            int i = 4 * c + k;
            int idx = (i < n) ? (pC[k] & 0x1FFFF) : ZROW;
            const ushort2* row = reinterpret_cast<const ushort2*>(
                hnbf + (size_t)idx * D);
            float2 v = bf22f2(row[sl]);
            int g = pC[k] >> 17;
            a0.x += v.x; a0.y += v.y;
            if (g >= 1) { a1.x += v.x; a1.y += v.y; }
            if (g >= 2) { a2.x += v.x; a2.y += v.y; }
        }
    }
    a0.x += __shfl_xor(a0.x, 32); a0.y += __shfl_xor(a0.y, 32);
    a1.x += __shfl_xor(a1.x, 32); a1.y += __shfl_xor(a1.y, 32);
    a2.x += __shfl_xor(a2.x, 32); a2.y += __shfl_xor(a2.y, 32);

    float2 r0 = ln_relu_pair(a0, true);
    float2 r1 = ln_relu_pair(a1, true);
    float2 r2 = ln_relu_pair(a2, true);

    float* ob = out + (size_t)node * 384;
    if (h == 0) {
        // interleaved write: cols c0=2sl, c1=2sl+1 -> 6 ushorts = dwordx3
        unsigned d0 = (unsigned)f2bfu(r0.x) | ((unsigned)f2bfu(r1.x) << 16);
        unsigned d1 = (unsigned)f2bfu(r2.x) | ((unsigned)f2bfu(r0.y) << 16);
        unsigned d2 = (unsigned)f2bfu(r1.y) | ((unsigned)f2bfu(r2.y) << 16);
        uint3v w = {d0, d1, d2};
        *reinterpret_cast<uint3v*>(A1i + (size_t)node * 192 + sl * 6) = w;
        reinterpret_cast<float2*>(ob + 64)[sl] = r0;           // out slot 1
    } else {
        float2 o4;
        o4.x = r0.x - 0.5f * (r1.x + r2.x);
        o4.y = r0.y - 0.5f * (r1.y + r2.y);
        reinterpret_cast<float2*>(ob + 256)[sl] = o4;          // out slot 4
    }
}

// layer-2 gather + LN/ReLU + remaining output slots. One dwordx3 per edge.
__global__ void gather2_kernel(const __hip_bfloat16* __restrict__ hnbf,
                               const unsigned short* __restrict__ A1i,
                               const int* __restrict__ cnt, const int* __restrict__ packed,
                               const int* __restrict__ age, float* __restrict__ out) {
    int gid  = blockIdx.x * blockDim.x + threadIdx.x;
    int node = gid >> 6;
    int lane = gid & 63;
    if (node >= NN) return;
    int sl = lane & 31;
    int h  = lane >> 5;
    int n  = min(cnt[node], CAP);
    int nc4 = (n + 3) >> 2;
    int mc  = max(nc4 - 1, 0);
    const int* pl = packed + (size_t)node * CAP;
    float2 a0 = {0.f, 0.f}, a1 = {0.f, 0.f}, a2 = {0.f, 0.f};

    {
        int c0 = min(h, mc), c1 = min(h + 2, mc);
        int4 pa = *reinterpret_cast<const int4*>(pl + 4 * c0);
        int4 pb = *reinterpret_cast<const int4*>(pl + 4 * c1);
        int pA[4] = {pa.x, pa.y, pa.z, pa.w};
        int pB[4] = {pb.x, pb.y, pb.z, pb.w};
        #pragma unroll
        for (int k = 0; k < 8; ++k) {
            int i  = (k < 4) ? (4 * h + k) : (4 * (h + 2) + (k - 4));
            int pk = (k < 4) ? pA[k] : pB[k - 4];
            int idx = (i < n) ? (pk & 0x1FFFF) : ZROW;
            uint3v w = *reinterpret_cast<const uint3v*>(
                A1i + (size_t)idx * 192 + sl * 6);
            a0.x += bfu2f(w.x & 0xffffu);  a0.y += bfu2f(w.y >> 16);
            a1.x += bfu2f(w.x >> 16);      a1.y += bfu2f(w.z & 0xffffu);
            a2.x += bfu2f(w.y & 0xffffu);  a2.y += bfu2f(w.z >> 16);
        }
    }
    for (int c = 4 + h; c < nc4; c += 2) {
        int4 pc = *reinterpret_cast<const int4*>(pl + 4 * c);
        int pC[4] = {pc.x, pc.y, pc.z, pc.w};
        #pragma unroll
        for (int k = 0; k < 4; ++k) {
            int i = 4 * c + k;
            int idx = (i < n) ? (pC[k] & 0x1FFFF) : ZROW;
            uint3v w = *reinterpret_cast<const uint3v*>(
                A1i + (size_t)idx * 192 + sl * 6);
            a0.x += bfu2f(w.x & 0xffffu);  a0.y += bfu2f(w.y >> 16);
            a1.x += bfu2f(w.x >> 16);      a1.y += bfu2f(w.z & 0xffffu);
            a2.x += bfu2f(w.y & 0xffffu);  a2.y += bfu2f(w.z >> 16);
        }
    }
    a0.x += __shfl_xor(a0.x, 32); a0.y += __shfl_xor(a0.y, 32);
    a1.x += __shfl_xor(a1.x, 32); a1.y += __shfl_xor(a1.y, 32);
    a2.x += __shfl_xor(a2.x, 32); a2.y += __shfl_xor(a2.y, 32);

    float2 h20 = ln_relu_pair(a0, true);
    float2 h21 = ln_relu_pair(a1, true);
    float2 h22 = ln_relu_pair(a2, true);

    float2 hnv = bf22f2(reinterpret_cast<const ushort2*>(
        hnbf + (size_t)node * D)[sl]);
    int ag = age[node];
    float f = 1.f - 0.5f * (float)((ag >= 1) + (ag >= 2));
    float* ob = out + (size_t)node * 384;
    if (h == 0) {
        reinterpret_cast<float2*>(ob)[sl] = hnv;               // slot 0
        reinterpret_cast<float2*>(ob + 128)[sl] = h20;         // slot 2
    } else {
        float2 o3, o5;
        o3.x = hnv.x * f;
        o3.y = hnv.y * f;
        o5.x = h20.x - 0.5f * (h21.x + h22.x);
        o5.y = h20.y - 0.5f * (h21.y + h22.y);
        reinterpret_cast<float2*>(ob + 192)[sl] = o3;          // slot 3
        reinterpret_cast<float2*>(ob + 320)[sl] = o5;          // slot 5
    }
}

extern "C" void kernel_launch(void* const* d_in, const int* in_sizes, int n_in,
                              void* d_out, int out_size, void* d_ws, size_t ws_size,
                              hipStream_t stream) {
    const float* feature = (const float*)d_in[0];
    const int*   age     = (const int*)d_in[1];
    const int*   src     = (const int*)d_in[2];
    const int*   dst     = (const int*)d_in[3];
    float* out = (float*)d_out;

    size_t nd1 = (size_t)(NN + 1) * D;               // hnbf rows incl. zero row
    __hip_bfloat16* hnbf = (__hip_bfloat16*)d_ws;    // [NN+1][D]      ~12.8 MB
    unsigned short* A1i  = (unsigned short*)(hnbf + nd1);  // [NN+1][64][3] ~38.4 MB
    int2* ebuf  = (int2*)(A1i + (size_t)(NN + 1) * 192);   // 8*EBCAP     10.24 MB (8B-aligned)
    int* cnt    = (int*)(ebuf + (size_t)NXCD * EBCAP);     // NN          0.4 MB
    int* packed = cnt + NN;                          // NN*CAP           25.6 MB
    unsigned* agePk = (unsigned*)(packed + (size_t)NN * CAP);   // 25 KB
    int* tail   = (int*)(agePk + NAPW);              // 8

    prep_kernel<<<(NN + 255) / 256, 256, 0, stream>>>(age, cnt, agePk, tail, hnbf, A1i);
    bucket_kernel<<<BUCKET_BLOCKS, 256, 0, stream>>>(src, dst, agePk, tail, ebuf);
    fill_ln_kernel<<<FILL_BLOCKS + LN_BLOCKS, 256, 0, stream>>>(
        ebuf, tail, feature, cnt, packed, hnbf);
    gather1_kernel<<<(NN * 64 + 255) / 256, 256, 0, stream>>>(hnbf, cnt, packed, A1i, out);
    gather2_kernel<<<(NN * 64 + 255) / 256, 256, 0, stream>>>(hnbf, A1i, cnt, packed,
                                                              age, out);
}

// Round 18
// 203.121 us; speedup vs baseline: 8.3920x; 8.3920x over previous
//
#include <hip/hip_runtime.h>
#include <hip/hip_bf16.h>

// SplitRoundGIN: N=100000, E=1200000, D=64, RW=3, L=2, eps=-1 (pure neighbor sum).
// R17 = revert to R14 (best: 205.6us). R15 (atomic ILP x8) neutral; R16
// (ballot bucketing) catastrophically regressed on same-address atomic
// serialization (~60ns each). Fill is pinned at device-atomic/scattered-store
// throughput; gathers at the L2-miss/L3-fill path (~3TB/s); LN at streaming BW.
constexpr int NN  = 100000;
constexpr int EE  = 1200000;
constexpr int D   = 64;
constexpr int CAP = 64;                  // max degree bucket (P(deg>64) ~ 1e-28)
constexpr int ZROW = NN;                 // dedicated all-zero row index
constexpr float LN_EPS = 1e-5f;
constexpr int NXCD = 8;
constexpr int NPX  = (NN + NXCD - 1) / NXCD;     // 12500 nodes per XCD range
constexpr int FILL_GRP = 256;                    // blocks per XCD group
constexpr int FILL_BLOCKS = NXCD * FILL_GRP;     // 2048
constexpr int LN_BLOCKS = (NN * D) / 256;        // 25000
constexpr int NAPW = (NN + 15) / 16;             // 6250 agePacked words

typedef unsigned uint3v __attribute__((ext_vector_type(3)));

// ---- prep: zero cnt, build agePk, zero ZROW rows of hnbf/A1i ----
__global__ void prep_kernel(const int* __restrict__ age, int* __restrict__ cnt,
                            unsigned* __restrict__ agePk,
                            __hip_bfloat16* __restrict__ ybf,
                            unsigned short* __restrict__ A1i) {
    int gid = blockIdx.x * blockDim.x + threadIdx.x;
    if (gid < NN) cnt[gid] = 0;
    if (gid < NAPW) {
        unsigned w = 0;
        int base = gid * 16;
        #pragma unroll
        for (int k = 0; k < 16; ++k) {
            int idx = base + k;
            unsigned a = (idx < NN) ? (unsigned)age[idx] : 0u;
            w |= (a & 3u) << (2 * k);
        }
        agePk[gid] = w;
    }
    if (gid < 192) {
        A1i[(size_t)ZROW * 192 + gid] = 0;
        if (gid < 64) ybf[(size_t)ZROW * D + gid] = __float2bfloat16(0.f);
    }
}

// ---- fused fill + LN (block-role split) ----
__global__ void fill_ln_kernel(const int* __restrict__ src, const int* __restrict__ dst,
                               const unsigned* __restrict__ agePk,
                               const float* __restrict__ x,
                               int* __restrict__ cnt, int* __restrict__ packed,
                               __hip_bfloat16* __restrict__ ybf) {
    int bid = blockIdx.x;
    if (bid < FILL_BLOCKS) {
        int xcd = bid & 7;               // -> XCD via round-robin dispatch
        int grp = bid >> 3;
        int lo = xcd * NPX;
        int hi = min(lo + NPX, NN);
        int per = (EE + FILL_GRP - 1) / FILL_GRP;
        int e0 = grp * per;
        int e1 = min(e0 + per, EE);
        for (int e = e0 + (int)threadIdx.x; e < e1; e += (int)blockDim.x) {
            int d = dst[e];
            if (d >= lo && d < hi) {
                int slot = atomicAdd(&cnt[d], 1);
                if (slot < CAP) {
                    int s = src[e];
                    unsigned aw = agePk[s >> 4];         // 25KB table: L1 hit
                    int ag = (aw >> ((s & 15) * 2)) & 3;
                    packed[(size_t)d * CAP + slot] = s | (ag << 17);
                }
            }
        }
        return;
    }
    // LN role
    int gid  = (bid - FILL_BLOCKS) * (int)blockDim.x + (int)threadIdx.x;
    int row  = gid >> 6;
    int lane = gid & 63;
    if (row >= NN) return;
    size_t i = (size_t)row * D + lane;
    float v = x[i];
    float s = v;
    #pragma unroll
    for (int m = 1; m < 64; m <<= 1) s += __shfl_xor(s, m);
    float mu = s * (1.f / 64.f);
    float d = v - mu;
    float q = d * d;
    #pragma unroll
    for (int m = 1; m < 64; m <<= 1) q += __shfl_xor(q, m);
    float r = d * rsqrtf(q * (1.f / 64.f) + LN_EPS);
    ybf[i] = __float2bfloat16(r);
}

__device__ __forceinline__ float2 bf22f2(ushort2 u) {
    float2 r;
    r.x = __uint_as_float((unsigned)u.x << 16);
    r.y = __uint_as_float((unsigned)u.y << 16);
    return r;
}

__device__ __forceinline__ float bfu2f(unsigned u) {
    return __uint_as_float(u << 16);
}

__device__ __forceinline__ unsigned short f2bfu(float v) {
    __hip_bfloat16 b = __float2bfloat16(v);
    return *(const unsigned short*)&b;
}

// Full-row LN over 64 cols held as float2 per lane in a 32-lane group.
__device__ __forceinline__ float2 ln_relu_pair(float2 a, bool relu) {
    float s = a.x + a.y;
    #pragma unroll
    for (int m = 1; m < 32; m <<= 1) s += __shfl_xor(s, m);
    float mu = s * (1.f / 64.f);
    float dx = a.x - mu, dy = a.y - mu;
    float q = dx * dx + dy * dy;
    #pragma unroll
    for (int m = 1; m < 32; m <<= 1) q += __shfl_xor(q, m);
    float rs = rsqrtf(q * (1.f / 64.f) + LN_EPS);
    float2 r;
    r.x = dx * rs;
    r.y = dy * rs;
    if (relu) { r.x = fmaxf(r.x, 0.f); r.y = fmaxf(r.y, 0.f); }
    return r;
}

// layer-1 gather (3 windows via age mask) + LN/ReLU + h1 output writes.
// A1i layout: [node][64][3] bf16 interleaved (384B/node; col c -> w0,w1,w2).
__global__ void gather1_kernel(const __hip_bfloat16* __restrict__ hnbf,
                               const int* __restrict__ cnt,
                               const int* __restrict__ packed,
                               unsigned short* __restrict__ A1i,
                               float* __restrict__ out) {
    int gid  = blockIdx.x * blockDim.x + threadIdx.x;
    int node = gid >> 6;
    int lane = gid & 63;
    if (node >= NN) return;
    int sl = lane & 31;
    int h  = lane >> 5;
    int n  = min(cnt[node], CAP);
    int nc4 = (n + 3) >> 2;
    int mc  = max(nc4 - 1, 0);
    const int* pl = packed + (size_t)node * CAP;   // 256B-aligned
    float2 a0 = {0.f, 0.f}, a1 = {0.f, 0.f}, a2 = {0.f, 0.f};

    {
        int c0 = min(h, mc), c1 = min(h + 2, mc);
        int4 pa = *reinterpret_cast<const int4*>(pl + 4 * c0);
        int4 pb = *reinterpret_cast<const int4*>(pl + 4 * c1);
        int pA[4] = {pa.x, pa.y, pa.z, pa.w};
        int pB[4] = {pb.x, pb.y, pb.z, pb.w};
        #pragma unroll
        for (int k = 0; k < 8; ++k) {
            int i  = (k < 4) ? (4 * h + k) : (4 * (h + 2) + (k - 4));
            int pk = (k < 4) ? pA[k] : pB[k - 4];
            int idx = (i < n) ? (pk & 0x1FFFF) : ZROW;
            const ushort2* row = reinterpret_cast<const ushort2*>(
                hnbf + (size_t)idx * D);
            float2 v = bf22f2(row[sl]);
            int g = pk >> 17;
            a0.x += v.x; a0.y += v.y;
            if (g >= 1) { a1.x += v.x; a1.y += v.y; }
            if (g >= 2) { a2.x += v.x; a2.y += v.y; }
        }
    }
    for (int c = 4 + h; c < nc4; c += 2) {
        int4 pc = *reinterpret_cast<const int4*>(pl + 4 * c);
        int pC[4] = {pc.x, pc.y, pc.z, pc.w};
        #pragma unroll
        for (int k = 0; k < 4; ++k) {
            int i = 4 * c + k;
            int idx = (i < n) ? (pC[k] & 0x1FFFF) : ZROW;
            const ushort2* row = reinterpret_cast<const ushort2*>(
                hnbf + (size_t)idx * D);
            float2 v = bf22f2(row[sl]);
            int g = pC[k] >> 17;
            a0.x += v.x; a0.y += v.y;
            if (g >= 1) { a1.x += v.x; a1.y += v.y; }
            if (g >= 2) { a2.x += v.x; a2.y += v.y; }
        }
    }
    a0.x += __shfl_xor(a0.x, 32); a0.y += __shfl_xor(a0.y, 32);
    a1.x += __shfl_xor(a1.x, 32); a1.y += __shfl_xor(a1.y, 32);
    a2.x += __shfl_xor(a2.x, 32); a2.y += __shfl_xor(a2.y, 32);

    float2 r0 = ln_relu_pair(a0, true);
    float2 r1 = ln_relu_pair(a1, true);
    float2 r2 = ln_relu_pair(a2, true);

    float* ob = out + (size_t)node * 384;
    if (h == 0) {
        // interleaved write: cols c0=2sl, c1=2sl+1 -> 6 ushorts = dwordx3
        unsigned d0 = (unsigned)f2bfu(r0.x) | ((unsigned)f2bfu(r1.x) << 16);
        unsigned d1 = (unsigned)f2bfu(r2.x) | ((unsigned)f2bfu(r0.y) << 16);
        unsigned d2 = (unsigned)f2bfu(r1.y) | ((unsigned)f2bfu(r2.y) << 16);
        uint3v w = {d0, d1, d2};
        *reinterpret_cast<uint3v*>(A1i + (size_t)node * 192 + sl * 6) = w;
        reinterpret_cast<float2*>(ob + 64)[sl] = r0;           // out slot 1
    } else {
        float2 o4;
        o4.x = r0.x - 0.5f * (r1.x + r2.x);
        o4.y = r0.y - 0.5f * (r1.y + r2.y);
        reinterpret_cast<float2*>(ob + 256)[sl] = o4;          // out slot 4
    }
}

// layer-2 gather + LN/ReLU + remaining output slots. One dwordx3 per edge.
__global__ void gather2_kernel(const __hip_bfloat16* __restrict__ hnbf,
                               const unsigned short* __restrict__ A1i,
                               const int* __restrict__ cnt, const int* __restrict__ packed,
                               const int* __restrict__ age, float* __restrict__ out) {
    int gid  = blockIdx.x * blockDim.x + threadIdx.x;
    int node = gid >> 6;
    int lane = gid & 63;
    if (node >= NN) return;
    int sl = lane & 31;
    int h  = lane >> 5;
    int n  = min(cnt[node], CAP);
    int nc4 = (n + 3) >> 2;
    int mc  = max(nc4 - 1, 0);
    const int* pl = packed + (size_t)node * CAP;
    float2 a0 = {0.f, 0.f}, a1 = {0.f, 0.f}, a2 = {0.f, 0.f};

    {
        int c0 = min(h, mc), c1 = min(h + 2, mc);
        int4 pa = *reinterpret_cast<const int4*>(pl + 4 * c0);
        int4 pb = *reinterpret_cast<const int4*>(pl + 4 * c1);
        int pA[4] = {pa.x, pa.y, pa.z, pa.w};
        int pB[4] = {pb.x, pb.y, pb.z, pb.w};
        #pragma unroll
        for (int k = 0; k < 8; ++k) {
            int i  = (k < 4) ? (4 * h + k) : (4 * (h + 2) + (k - 4));
            int pk = (k < 4) ? pA[k] : pB[k - 4];
            int idx = (i < n) ? (pk & 0x1FFFF) : ZROW;
            uint3v w = *reinterpret_cast<const uint3v*>(
                A1i + (size_t)idx * 192 + sl * 6);
            a0.x += bfu2f(w.x & 0xffffu);  a0.y += bfu2f(w.y >> 16);
            a1.x += bfu2f(w.x >> 16);      a1.y += bfu2f(w.z & 0xffffu);
            a2.x += bfu2f(w.y & 0xffffu);  a2.y += bfu2f(w.z >> 16);
        }
    }
    for (int c = 4 + h; c < nc4; c += 2) {
        int4 pc = *reinterpret_cast<const int4*>(pl + 4 * c);
        int pC[4] = {pc.x, pc.y, pc.z, pc.w};
        #pragma unroll
        for (int k = 0; k < 4; ++k) {
            int i = 4 * c + k;
            int idx = (i < n) ? (pC[k] & 0x1FFFF) : ZROW;
            uint3v w = *reinterpret_cast<const uint3v*>(
                A1i + (size_t)idx * 192 + sl * 6);
            a0.x += bfu2f(w.x & 0xffffu);  a0.y += bfu2f(w.y >> 16);
            a1.x += bfu2f(w.x >> 16);      a1.y += bfu2f(w.z & 0xffffu);
            a2.x += bfu2f(w.y & 0xffffu);  a2.y += bfu2f(w.z >> 16);
        }
    }
    a0.x += __shfl_xor(a0.x, 32); a0.y += __shfl_xor(a0.y, 32);
    a1.x += __shfl_xor(a1.x, 32); a1.y += __shfl_xor(a1.y, 32);
    a2.x += __shfl_xor(a2.x, 32); a2.y += __shfl_xor(a2.y, 32);

    float2 h20 = ln_relu_pair(a0, true);
    float2 h21 = ln_relu_pair(a1, true);
    float2 h22 = ln_relu_pair(a2, true);

    float2 hnv = bf22f2(reinterpret_cast<const ushort2*>(
        hnbf + (size_t)node * D)[sl]);
    int ag = age[node];
    float f = 1.f - 0.5f * (float)((ag >= 1) + (ag >= 2));
    float* ob = out + (size_t)node * 384;
    if (h == 0) {
        reinterpret_cast<float2*>(ob)[sl] = hnv;               // slot 0
        reinterpret_cast<float2*>(ob + 128)[sl] = h20;         // slot 2
    } else {
        float2 o3, o5;
        o3.x = hnv.x * f;
        o3.y = hnv.y * f;
        o5.x = h20.x - 0.5f * (h21.x + h22.x);
        o5.y = h20.y - 0.5f * (h21.y + h22.y);
        reinterpret_cast<float2*>(ob + 192)[sl] = o3;          // slot 3
        reinterpret_cast<float2*>(ob + 320)[sl] = o5;          // slot 5
    }
}

extern "C" void kernel_launch(void* const* d_in, const int* in_sizes, int n_in,
                              void* d_out, int out_size, void* d_ws, size_t ws_size,
                              hipStream_t stream) {
    const float* feature = (const float*)d_in[0];
    const int*   age     = (const int*)d_in[1];
    const int*   src     = (const int*)d_in[2];
    const int*   dst     = (const int*)d_in[3];
    float* out = (float*)d_out;

    size_t nd1 = (size_t)(NN + 1) * D;               // hnbf rows incl. zero row
    __hip_bfloat16* hnbf = (__hip_bfloat16*)d_ws;    // [NN+1][D]      ~12.8 MB
    unsigned short* A1i  = (unsigned short*)(hnbf + nd1);  // [NN+1][64][3] ~38.4 MB
    int* cnt    = (int*)(A1i + (size_t)(NN + 1) * 192);    // NN        0.4 MB
    int* packed = cnt + NN;                          // NN*CAP          25.6 MB
    unsigned* agePk = (unsigned*)(packed + (size_t)NN * CAP);   // 25 KB

    prep_kernel<<<(NN + 255) / 256, 256, 0, stream>>>(age, cnt, agePk, hnbf, A1i);
    fill_ln_kernel<<<FILL_BLOCKS + LN_BLOCKS, 256, 0, stream>>>(
        src, dst, agePk, feature, cnt, packed, hnbf);
    gather1_kernel<<<(NN * 64 + 255) / 256, 256, 0, stream>>>(hnbf, cnt, packed, A1i, out);
    gather2_kernel<<<(NN * 64 + 255) / 256, 256, 0, stream>>>(hnbf, A1i, cnt, packed,
                                                              age, out);
}